// Round 19
// baseline (98.657 us; speedup 1.0000x reference)
//
#include <hip/hip_runtime.h>
#include <hip/hip_bf16.h>

typedef unsigned short u16;
typedef unsigned int u32;
typedef __bf16 bf16;
typedef __attribute__((ext_vector_type(8))) __bf16 bf16x8;
typedef __attribute__((ext_vector_type(4))) __bf16 bf16x4;
typedef __attribute__((ext_vector_type(4))) float f32x4;

#define MFMA16(A,B,C) __builtin_amdgcn_mfma_f32_16x16x32_bf16(A,B,C,0,0,0)

constexpr int NTOK = 49;
constexpr int CH   = 128;
// softmax scale folded into exp2: SCALE * log2(e)
constexpr float CEXP = 0.17677669529663687f * 1.4426950408889634f;

__device__ __forceinline__ bf16x8 lds_v8(const char* p) {
    return *reinterpret_cast<const bf16x8*>(p);
}
__device__ __forceinline__ void lds_st64(char* p, float a0, float a1, float a2, float a3) {
    bf16x4 v = {(bf16)a0, (bf16)a1, (bf16)a2, (bf16)a3};
    *reinterpret_cast<bf16x4*>(p) = v;
}
__device__ __forceinline__ u32 pkbf(float a, float b) {
    u16 lo = __builtin_bit_cast(u16, (bf16)a);
    u16 hi = __builtin_bit_cast(u16, (bf16)b);
    return (u32)lo | ((u32)hi << 16);
}

// D-layout -> A/B-frag layout cross-lane exchange (verified r12).
__device__ __forceinline__ bf16x8 xchg(u32 lo0, u32 lo1, u32 hi0, u32 hi1,
                                       int srcA, int srcB, bool hiT) {
    u32 a0 = __shfl(lo0, srcA), b0 = __shfl(hi0, srcA);
    u32 a1 = __shfl(lo1, srcA), b1 = __shfl(hi1, srcA);
    u32 a2 = __shfl(lo0, srcB), b2 = __shfl(hi0, srcB);
    u32 a3 = __shfl(lo1, srcB), b3 = __shfl(hi1, srcB);
    uint4 u = { hiT ? b0 : a0, hiT ? b1 : a1, hiT ? b2 : a2, hiT ? b3 : a3 };
    return __builtin_bit_cast(bf16x8, u);
}

// Weights fp32 -> bf16, transposed: ws = Wqkv_t[384][128] then Wproj_t[128][128]
__global__ void prep_weights_kernel(const float* __restrict__ wqkv,
                                    const float* __restrict__ wproj,
                                    bf16* __restrict__ ws) {
    int i = blockIdx.x * 256 + threadIdx.x;
    if (i < 384 * 128) {
        int n = i >> 7, k = i & 127;
        ws[i] = (bf16)wqkv[k * 384 + n];
    }
    if (i < 128 * 128) {
        int n = i >> 7, k = i & 127;
        ws[384 * 128 + i] = (bf16)wproj[k * 128 + n];
    }
}

// r15/r17 measured optimum (89.6-90.0 us) + non-temporal cache policy on the
// single-use streams (x loads, out stores) via ext_vector f32x4 pointers
// (r18 lesson: the nontemporal builtins reject HIP_vector_type structs).
//
// Structural constraints (measured, r5-r17):
//  - allocator splits wave budget ~50/50 arch/acc at every tier:
//    (256,4)->64+64; (256,5)->48+48(spills); (256,3)->85+85.
//  - this kernel sits EXACTLY at the 64-arch ceiling via LDS remat of xf;
//    any extra persistent arch value (prefetch regs, V-in-regs, fused QKV)
//    spills: r8/r9/r14/r16 all measured.
//  - occupancy tiers: 3 blk (97us), 4 blk (THIS, 90us), 8-wave (235us),
//    5 blk unreachable (reg split + LDS granularity).
// LDS = 32,768 B -> (256,4) = 4 blocks/CU.
//  [0,16384):     Xs [64 tok][128 ch] swz((row&7)<<4); ALIAS (post-B3) O tile.
//  [16384,32768): V slabs Vb(h)=16384+h*4096: [32 dh][64 s], 128B rows,
//                 swz((dh&7)<<4). Wave-local -> no barrier.
// Barriers: B1 (stage), B3 (X reads done block-wide), B4 (O tile ready).
__launch_bounds__(256, 4)
__global__ void fused_window_attn(const float* __restrict__ x,
                                  const bf16* __restrict__ wqkv_t,
                                  const bf16* __restrict__ wproj_t,
                                  const float* __restrict__ bias,
                                  float* __restrict__ out) {
    __shared__ __align__(16) u16 smem[16384];   // 32,768 B
    char* S8 = reinterpret_cast<char*>(smem);

    const int tid  = threadIdx.x;
    const int blk  = blockIdx.x;
    const int h    = tid >> 6;    // wave == head
    const int lane = tid & 63;
    const int lr   = lane & 15;
    const int lg   = lane >> 4;
    const int srcA = lr + 32 * (lg & 1);
    const int srcB = srcA + 16;
    const bool hiT = (lg >= 2);

    char* Vb = S8 + 16384 + h * 4096;

    // ---------- phase 0: stage x -> Xs (bf16, swizzled); zero pad rows ----------
    const float* xw = x + (size_t)blk * (NTOK * CH);
    #pragma unroll
    for (int it = 0; it < 7; ++it) {
        int i = tid + it * 256;
        if (i < (NTOK * CH) / 4) {
            f32x4 v = __builtin_nontemporal_load(
                reinterpret_cast<const f32x4*>(xw) + i);
            int e = i * 4, row = e >> 7, col = e & 127;
            bf16x4 pk4 = { (bf16)v[0], (bf16)v[1], (bf16)v[2], (bf16)v[3] };
            *reinterpret_cast<bf16x4*>(S8 + row * 256 + ((col * 2) ^ ((row & 7) << 4))) = pk4;
        }
    }
    if (tid < 240) {  // rows 49..63 exact zeros (whole rows -> swizzle-invariant)
        uint4 zz = {0, 0, 0, 0};
        *reinterpret_cast<uint4*>(S8 + 49 * 256 + tid * 16) = zz;
    }

    // V-phase weight frags: issue BEFORE the barrier (independent global loads
    // overlap the stage drain).
    bf16x8 wfv[2][4];
    #pragma unroll
    for (int half = 0; half < 2; ++half) {
        const bf16* wrow = wqkv_t + ((16 + 2 * h + half) * 16 + lr) * 128 + lg * 8;
        #pragma unroll
        for (int ks = 0; ks < 4; ++ks)
            wfv[half][ks] = *reinterpret_cast<const bf16x8*>(wrow + ks * 32);
    }
    __syncthreads();  // B1

    // ---------- X -> registers (A and B fragments share bytes) ----------
    bf16x8 xf[4][4];  // [tok-tile][kstep]
    #pragma unroll
    for (int tt = 0; tt < 4; ++tt)
        #pragma unroll
        for (int ks = 0; ks < 4; ++ks) {
            int row = tt * 16 + lr;
            xf[tt][ks] = lds_v8(S8 + row * 256 + ((ks * 64 + lg * 16) ^ ((row & 7) << 4)));
        }

    __builtin_amdgcn_s_setprio(1);
    // ---------- V GEMM first (results to LDS slab, no held frags) ----------
    #pragma unroll
    for (int i = 0; i < 2; ++i) {
        int dh = i * 16 + lr;
        #pragma unroll
        for (int tt = 0; tt < 4; ++tt) {
            f32x4 a = {0.f, 0.f, 0.f, 0.f};
            #pragma unroll
            for (int ks = 0; ks < 4; ++ks) a = MFMA16(xf[tt][ks], wfv[i][ks], a);
            lds_st64(Vb + dh * 128 + ((tt * 32 + lg * 8) ^ ((dh & 7) << 4)),
                     a[0], a[1], a[2], a[3]);
        }
    }

    // ---------- Q GEMM -> in-register frags via xchg ----------
    bf16x8 qf[4];
    {
        u32 pkq[2][4][2];
        #pragma unroll
        for (int half = 0; half < 2; ++half) {
            int ct = 2 * h + half;
            bf16x8 wf[4];
            const bf16* wrow = wqkv_t + (ct * 16 + lr) * 128 + lg * 8;
            #pragma unroll
            for (int ks = 0; ks < 4; ++ks)
                wf[ks] = *reinterpret_cast<const bf16x8*>(wrow + ks * 32);
            #pragma unroll
            for (int tt = 0; tt < 4; ++tt) {
                f32x4 a = {0.f, 0.f, 0.f, 0.f};
                #pragma unroll
                for (int ks = 0; ks < 4; ++ks) a = MFMA16(wf[ks], xf[tt][ks], a);
                pkq[half][tt][0] = pkbf(a[0], a[1]);
                pkq[half][tt][1] = pkbf(a[2], a[3]);
            }
        }
        #pragma unroll
        for (int tt = 0; tt < 4; ++tt)
            qf[tt] = xchg(pkq[0][tt][0], pkq[0][tt][1],
                          pkq[1][tt][0], pkq[1][tt][1], srcA, srcB, hiT);
    }
    // ---------- K GEMM -> in-register frags via xchg ----------
    bf16x8 kf[4];
    {
        u32 pkk[2][4][2];
        #pragma unroll
        for (int half = 0; half < 2; ++half) {
            int ct = 8 + 2 * h + half;
            bf16x8 wf[4];
            const bf16* wrow = wqkv_t + (ct * 16 + lr) * 128 + lg * 8;
            #pragma unroll
            for (int ks = 0; ks < 4; ++ks)
                wf[ks] = *reinterpret_cast<const bf16x8*>(wrow + ks * 32);
            #pragma unroll
            for (int tt = 0; tt < 4; ++tt) {
                f32x4 a = {0.f, 0.f, 0.f, 0.f};
                #pragma unroll
                for (int ks = 0; ks < 4; ++ks) a = MFMA16(wf[ks], xf[tt][ks], a);
                pkk[half][tt][0] = pkbf(a[0], a[1]);
                pkk[half][tt][1] = pkbf(a[2], a[3]);
            }
        }
        #pragma unroll
        for (int tt = 0; tt < 4; ++tt)
            kf[tt] = xchg(pkk[0][tt][0], pkk[0][tt][1],
                          pkk[1][tt][0], pkk[1][tt][1], srcA, srcB, hiT);
    }
    __builtin_amdgcn_s_setprio(0);

    // V fragments (own slab; wave-local RAW, no barrier needed)
    bf16x8 vf[2][2];
    #pragma unroll
    for (int dht = 0; dht < 2; ++dht)
        #pragma unroll
        for (int ks2 = 0; ks2 < 2; ++ks2) {
            int dh = dht * 16 + lr;
            vf[dht][ks2] = lds_v8(Vb + dh * 128 + ((ks2 * 64 + lg * 16) ^ ((dh & 7) << 4)));
        }
    __syncthreads();  // B3: all waves past xf loads; O may now clobber X region

    // ones A-fragment for the MFMA row-sum
    bf16x8 ones;
    #pragma unroll
    for (int j = 0; j < 8; ++j) ones[j] = (bf16)1.0f;

    // ---------- per-qt: S^T = K @ Q^T, no-max softmax, pf via xchg, PV, O ----------
    #pragma unroll
    for (int qt = 0; qt < 4; ++qt) {
        f32x4 s[4];
        __builtin_amdgcn_s_setprio(1);
        #pragma unroll
        for (int st = 0; st < 4; ++st) {
            f32x4 z = {0.f, 0.f, 0.f, 0.f};
            s[st] = MFMA16(kf[st], qf[qt], z);  // lane col = q, regs = s rows
        }
        __builtin_amdgcn_s_setprio(0);
        // no-max softmax (S~N(0,1), |S|max~6 -> exp2 safe); mask pad s>=49
        #pragma unroll
        for (int st = 0; st < 3; ++st)
            #pragma unroll
            for (int rg = 0; rg < 4; ++rg)
                s[st][rg] = exp2f(s[st][rg] * CEXP);
        {   // st=3: s = 48 + 4*lg + rg; only s==48 (lg==0,rg==0) valid
            float e48 = exp2f(s[3][0] * CEXP);
            s[3][0] = (lg == 0) ? e48 : 0.f;
            s[3][1] = 0.f; s[3][2] = 0.f; s[3][3] = 0.f;
        }

        // P -> B-frags in-register
        u32 pks[4][2];
        #pragma unroll
        for (int st = 0; st < 4; ++st) {
            pks[st][0] = pkbf(s[st][0], s[st][1]);
            pks[st][1] = pkbf(s[st][2], s[st][3]);
        }
        bf16x8 pf0 = xchg(pks[0][0], pks[0][1], pks[1][0], pks[1][1], srcA, srcB, hiT);
        bf16x8 pf1 = xchg(pks[2][0], pks[2][1], pks[3][0], pks[3][1], srcA, srcB, hiT);

        // row-sum on the MFMA pipe: l[q] = sum_s P[s][q] (pad cols are exact 0;
        // bf16-P sum is self-consistent with the bf16 PV product below)
        __builtin_amdgcn_s_setprio(1);
        f32x4 lacc = {0.f, 0.f, 0.f, 0.f};
        lacc = MFMA16(ones, pf0, lacc);
        lacc = MFMA16(ones, pf1, lacc);

        // O^T = V^T @ P^T for this qt: lane col = q, regs = 4 consecutive dh
        f32x4 o0 = {0.f, 0.f, 0.f, 0.f}, o1 = {0.f, 0.f, 0.f, 0.f};
        o0 = MFMA16(vf[0][0], pf0, o0);
        o1 = MFMA16(vf[1][0], pf0, o1);
        o0 = MFMA16(vf[0][1], pf1, o0);
        o1 = MFMA16(vf[1][1], pf1, o1);
        __builtin_amdgcn_s_setprio(0);
        float rs = 1.f / lacc[0];   // every reg of lacc holds the same sum

        // O rows -> X region [tok][ch], packed b64, rescaled
        int q = qt * 16 + lr;
        lds_st64(S8 + q * 256 + ((h * 64 + lg * 8) ^ ((q & 7) << 4)),
                 o0[0] * rs, o0[1] * rs, o0[2] * rs, o0[3] * rs);
        lds_st64(S8 + q * 256 + ((h * 64 + 32 + lg * 8) ^ ((q & 7) << 4)),
                 o1[0] * rs, o1[1] * rs, o1[2] * rs, o1[3] * rs);
    }
    __syncthreads();  // B4

    // ---------- proj GEMM + bias -> f32x4 non-temporal out ----------
    bf16x8 ofr[4][4];
    #pragma unroll
    for (int tt = 0; tt < 4; ++tt)
        #pragma unroll
        for (int ks = 0; ks < 4; ++ks) {
            int row = tt * 16 + lr;
            ofr[tt][ks] = lds_v8(S8 + row * 256 + ((ks * 64 + lg * 16) ^ ((row & 7) << 4)));
        }
    #pragma unroll
    for (int i = 0; i < 2; ++i) {
        int ct = 2 * h + i;
        bf16x8 wf[4];
        const bf16* wrow = wproj_t + (ct * 16 + lr) * 128 + lg * 8;
        #pragma unroll
        for (int ks = 0; ks < 4; ++ks)
            wf[ks] = *reinterpret_cast<const bf16x8*>(wrow + ks * 32);
        f32x4 bv = *reinterpret_cast<const f32x4*>(bias + ct * 16 + lg * 4);
        __builtin_amdgcn_s_setprio(1);
        #pragma unroll
        for (int tt = 0; tt < 4; ++tt) {
            f32x4 a = {0.f, 0.f, 0.f, 0.f};
            #pragma unroll
            for (int ks = 0; ks < 4; ++ks) a = MFMA16(wf[ks], ofr[tt][ks], a);
            int tok = tt * 16 + lr;
            if (tok < NTOK) {
                f32x4 r = { a[0] + bv[0], a[1] + bv[1], a[2] + bv[2], a[3] + bv[3] };
                __builtin_nontemporal_store(r,
                    reinterpret_cast<f32x4*>(
                        out + ((size_t)blk * NTOK + tok) * CH + ct * 16 + lg * 4));
            }
        }
        __builtin_amdgcn_s_setprio(0);
    }
}

extern "C" void kernel_launch(void* const* d_in, const int* in_sizes, int n_in,
                              void* d_out, int out_size, void* d_ws, size_t ws_size,
                              hipStream_t stream) {
    const float* x     = (const float*)d_in[0];
    const float* wqkv  = (const float*)d_in[1];
    const float* wproj = (const float*)d_in[2];
    const float* bias  = (const float*)d_in[3];
    float* out = (float*)d_out;
    bf16* ws   = (bf16*)d_ws;

    constexpr size_t WS_NEED = (size_t)(384 * 128 + 128 * 128) * sizeof(u16);
    if (ws_size < WS_NEED) return;

    prep_weights_kernel<<<192, 256, 0, stream>>>(wqkv, wproj, ws);
    fused_window_attn<<<4096, 256, 0, stream>>>(x, ws, ws + 384 * 128, bias, out);
}

// Round 20
// 89.572 us; speedup vs baseline: 1.1014x; 1.1014x over previous
//
#include <hip/hip_runtime.h>
#include <hip/hip_bf16.h>

typedef unsigned short u16;
typedef unsigned int u32;
typedef __bf16 bf16;
typedef __attribute__((ext_vector_type(8))) __bf16 bf16x8;
typedef __attribute__((ext_vector_type(4))) __bf16 bf16x4;
typedef __attribute__((ext_vector_type(4))) float f32x4;

#define MFMA16(A,B,C) __builtin_amdgcn_mfma_f32_16x16x32_bf16(A,B,C,0,0,0)

constexpr int NTOK = 49;
constexpr int CH   = 128;
// softmax scale folded into exp2: SCALE * log2(e)
constexpr float CEXP = 0.17677669529663687f * 1.4426950408889634f;

__device__ __forceinline__ bf16x8 lds_v8(const char* p) {
    return *reinterpret_cast<const bf16x8*>(p);
}
__device__ __forceinline__ void lds_st64(char* p, float a0, float a1, float a2, float a3) {
    bf16x4 v = {(bf16)a0, (bf16)a1, (bf16)a2, (bf16)a3};
    *reinterpret_cast<bf16x4*>(p) = v;
}
__device__ __forceinline__ u32 pkbf(float a, float b) {
    u16 lo = __builtin_bit_cast(u16, (bf16)a);
    u16 hi = __builtin_bit_cast(u16, (bf16)b);
    return (u32)lo | ((u32)hi << 16);
}

// D-layout -> A/B-frag layout cross-lane exchange (verified r12).
__device__ __forceinline__ bf16x8 xchg(u32 lo0, u32 lo1, u32 hi0, u32 hi1,
                                       int srcA, int srcB, bool hiT) {
    u32 a0 = __shfl(lo0, srcA), b0 = __shfl(hi0, srcA);
    u32 a1 = __shfl(lo1, srcA), b1 = __shfl(hi1, srcA);
    u32 a2 = __shfl(lo0, srcB), b2 = __shfl(hi0, srcB);
    u32 a3 = __shfl(lo1, srcB), b3 = __shfl(hi1, srcB);
    uint4 u = { hiT ? b0 : a0, hiT ? b1 : a1, hiT ? b2 : a2, hiT ? b3 : a3 };
    return __builtin_bit_cast(bf16x8, u);
}

// Weights fp32 -> bf16, transposed: ws = Wqkv_t[384][128] then Wproj_t[128][128]
__global__ void prep_weights_kernel(const float* __restrict__ wqkv,
                                    const float* __restrict__ wproj,
                                    bf16* __restrict__ ws) {
    int i = blockIdx.x * 256 + threadIdx.x;
    if (i < 384 * 128) {
        int n = i >> 7, k = i & 127;
        ws[i] = (bf16)wqkv[k * 384 + n];
    }
    if (i < 128 * 128) {
        int n = i >> 7, k = i & 127;
        ws[384 * 128 + i] = (bf16)wproj[k * 128 + n];
    }
}

// FINAL — r15/r17 measured optimum (89.6/90.0 us, reproduced twice).
// 4 waves/block, wave == head, 16x16x32 MFMA; Q/K/P in REGISTERS via xchg;
// no-max softmax; row-sum l via MFMA(ones,pf); V-weight frags hoisted pre-B1.
// LDS = 32,768 B -> (256,4) = 4 blocks/CU.
//
// Design-space closure (all measured):
//  - register model: allocator splits wave budget ~50/50 arch/acc per tier
//    ((256,4)->64+64, (256,5)->48+48 spills, (256,3)->85+85); this kernel
//    sits exactly at the 64-arch ceiling via LDS remat of xf. Any extra
//    persistent arch value spills (r8/r9/r14/r16: prefetch, V-in-regs,
//    fused QKV, 2-window pipeline -> 137-2258 MB scratch traffic).
//  - occupancy tiers: 3 blk 97us, 4 blk 90us (THIS), 8-wave 235us,
//    5 blk unreachable.
//  - dataflows: LDS-flow 97us, 32x32-reg 103us, 16x16-reg-xchg 90us (THIS).
//  - cache policy: nt loads/stores regress (r19: +15MB write, +9us — L2
//    write-coalescing is load-bearing for the fragmented out stores).
// Latency-bound structural floor (HBM 17%, MfmaUtil 16%), not a roofline.
//  [0,16384):     Xs [64 tok][128 ch] swz((row&7)<<4); ALIAS (post-B3) O tile.
//  [16384,32768): V slabs Vb(h)=16384+h*4096: [32 dh][64 s], 128B rows,
//                 swz((dh&7)<<4). Wave-local -> no barrier.
// Barriers: B1 (stage), B3 (X reads done block-wide), B4 (O tile ready).
__launch_bounds__(256, 4)
__global__ void fused_window_attn(const float* __restrict__ x,
                                  const bf16* __restrict__ wqkv_t,
                                  const bf16* __restrict__ wproj_t,
                                  const float* __restrict__ bias,
                                  float* __restrict__ out) {
    __shared__ __align__(16) u16 smem[16384];   // 32,768 B
    char* S8 = reinterpret_cast<char*>(smem);

    const int tid  = threadIdx.x;
    const int blk  = blockIdx.x;
    const int h    = tid >> 6;    // wave == head
    const int lane = tid & 63;
    const int lr   = lane & 15;
    const int lg   = lane >> 4;
    const int srcA = lr + 32 * (lg & 1);
    const int srcB = srcA + 16;
    const bool hiT = (lg >= 2);

    char* Vb = S8 + 16384 + h * 4096;

    // ---------- phase 0: stage x -> Xs (bf16, swizzled); zero pad rows ----------
    const float* xw = x + (size_t)blk * (NTOK * CH);
    #pragma unroll
    for (int it = 0; it < 7; ++it) {
        int i = tid + it * 256;
        if (i < (NTOK * CH) / 4) {
            float4 v = reinterpret_cast<const float4*>(xw)[i];
            int e = i * 4, row = e >> 7, col = e & 127;
            bf16x4 pk4 = { (bf16)v.x, (bf16)v.y, (bf16)v.z, (bf16)v.w };
            *reinterpret_cast<bf16x4*>(S8 + row * 256 + ((col * 2) ^ ((row & 7) << 4))) = pk4;
        }
    }
    if (tid < 240) {  // rows 49..63 exact zeros (whole rows -> swizzle-invariant)
        uint4 zz = {0, 0, 0, 0};
        *reinterpret_cast<uint4*>(S8 + 49 * 256 + tid * 16) = zz;
    }

    // V-phase weight frags: issue BEFORE the barrier (independent global loads
    // overlap the stage drain).
    bf16x8 wfv[2][4];
    #pragma unroll
    for (int half = 0; half < 2; ++half) {
        const bf16* wrow = wqkv_t + ((16 + 2 * h + half) * 16 + lr) * 128 + lg * 8;
        #pragma unroll
        for (int ks = 0; ks < 4; ++ks)
            wfv[half][ks] = *reinterpret_cast<const bf16x8*>(wrow + ks * 32);
    }
    __syncthreads();  // B1

    // ---------- X -> registers (A and B fragments share bytes) ----------
    bf16x8 xf[4][4];  // [tok-tile][kstep]
    #pragma unroll
    for (int tt = 0; tt < 4; ++tt)
        #pragma unroll
        for (int ks = 0; ks < 4; ++ks) {
            int row = tt * 16 + lr;
            xf[tt][ks] = lds_v8(S8 + row * 256 + ((ks * 64 + lg * 16) ^ ((row & 7) << 4)));
        }

    __builtin_amdgcn_s_setprio(1);
    // ---------- V GEMM first (results to LDS slab, no held frags) ----------
    #pragma unroll
    for (int i = 0; i < 2; ++i) {
        int dh = i * 16 + lr;
        #pragma unroll
        for (int tt = 0; tt < 4; ++tt) {
            f32x4 a = {0.f, 0.f, 0.f, 0.f};
            #pragma unroll
            for (int ks = 0; ks < 4; ++ks) a = MFMA16(xf[tt][ks], wfv[i][ks], a);
            lds_st64(Vb + dh * 128 + ((tt * 32 + lg * 8) ^ ((dh & 7) << 4)),
                     a[0], a[1], a[2], a[3]);
        }
    }

    // ---------- Q GEMM -> in-register frags via xchg ----------
    bf16x8 qf[4];
    {
        u32 pkq[2][4][2];
        #pragma unroll
        for (int half = 0; half < 2; ++half) {
            int ct = 2 * h + half;
            bf16x8 wf[4];
            const bf16* wrow = wqkv_t + (ct * 16 + lr) * 128 + lg * 8;
            #pragma unroll
            for (int ks = 0; ks < 4; ++ks)
                wf[ks] = *reinterpret_cast<const bf16x8*>(wrow + ks * 32);
            #pragma unroll
            for (int tt = 0; tt < 4; ++tt) {
                f32x4 a = {0.f, 0.f, 0.f, 0.f};
                #pragma unroll
                for (int ks = 0; ks < 4; ++ks) a = MFMA16(wf[ks], xf[tt][ks], a);
                pkq[half][tt][0] = pkbf(a[0], a[1]);
                pkq[half][tt][1] = pkbf(a[2], a[3]);
            }
        }
        #pragma unroll
        for (int tt = 0; tt < 4; ++tt)
            qf[tt] = xchg(pkq[0][tt][0], pkq[0][tt][1],
                          pkq[1][tt][0], pkq[1][tt][1], srcA, srcB, hiT);
    }
    // ---------- K GEMM -> in-register frags via xchg ----------
    bf16x8 kf[4];
    {
        u32 pkk[2][4][2];
        #pragma unroll
        for (int half = 0; half < 2; ++half) {
            int ct = 8 + 2 * h + half;
            bf16x8 wf[4];
            const bf16* wrow = wqkv_t + (ct * 16 + lr) * 128 + lg * 8;
            #pragma unroll
            for (int ks = 0; ks < 4; ++ks)
                wf[ks] = *reinterpret_cast<const bf16x8*>(wrow + ks * 32);
            #pragma unroll
            for (int tt = 0; tt < 4; ++tt) {
                f32x4 a = {0.f, 0.f, 0.f, 0.f};
                #pragma unroll
                for (int ks = 0; ks < 4; ++ks) a = MFMA16(wf[ks], xf[tt][ks], a);
                pkk[half][tt][0] = pkbf(a[0], a[1]);
                pkk[half][tt][1] = pkbf(a[2], a[3]);
            }
        }
        #pragma unroll
        for (int tt = 0; tt < 4; ++tt)
            kf[tt] = xchg(pkk[0][tt][0], pkk[0][tt][1],
                          pkk[1][tt][0], pkk[1][tt][1], srcA, srcB, hiT);
    }
    __builtin_amdgcn_s_setprio(0);

    // V fragments (own slab; wave-local RAW, no barrier needed)
    bf16x8 vf[2][2];
    #pragma unroll
    for (int dht = 0; dht < 2; ++dht)
        #pragma unroll
        for (int ks2 = 0; ks2 < 2; ++ks2) {
            int dh = dht * 16 + lr;
            vf[dht][ks2] = lds_v8(Vb + dh * 128 + ((ks2 * 64 + lg * 16) ^ ((dh & 7) << 4)));
        }
    __syncthreads();  // B3: all waves past xf loads; O may now clobber X region

    // ones A-fragment for the MFMA row-sum
    bf16x8 ones;
    #pragma unroll
    for (int j = 0; j < 8; ++j) ones[j] = (bf16)1.0f;

    // ---------- per-qt: S^T = K @ Q^T, no-max softmax, pf via xchg, PV, O ----------
    #pragma unroll
    for (int qt = 0; qt < 4; ++qt) {
        f32x4 s[4];
        __builtin_amdgcn_s_setprio(1);
        #pragma unroll
        for (int st = 0; st < 4; ++st) {
            f32x4 z = {0.f, 0.f, 0.f, 0.f};
            s[st] = MFMA16(kf[st], qf[qt], z);  // lane col = q, regs = s rows
        }
        __builtin_amdgcn_s_setprio(0);
        // no-max softmax (S~N(0,1), |S|max~6 -> exp2 safe); mask pad s>=49
        #pragma unroll
        for (int st = 0; st < 3; ++st)
            #pragma unroll
            for (int rg = 0; rg < 4; ++rg)
                s[st][rg] = exp2f(s[st][rg] * CEXP);
        {   // st=3: s = 48 + 4*lg + rg; only s==48 (lg==0,rg==0) valid
            float e48 = exp2f(s[3][0] * CEXP);
            s[3][0] = (lg == 0) ? e48 : 0.f;
            s[3][1] = 0.f; s[3][2] = 0.f; s[3][3] = 0.f;
        }

        // P -> B-frags in-register
        u32 pks[4][2];
        #pragma unroll
        for (int st = 0; st < 4; ++st) {
            pks[st][0] = pkbf(s[st][0], s[st][1]);
            pks[st][1] = pkbf(s[st][2], s[st][3]);
        }
        bf16x8 pf0 = xchg(pks[0][0], pks[0][1], pks[1][0], pks[1][1], srcA, srcB, hiT);
        bf16x8 pf1 = xchg(pks[2][0], pks[2][1], pks[3][0], pks[3][1], srcA, srcB, hiT);

        // row-sum on the MFMA pipe: l[q] = sum_s P[s][q] (pad cols are exact 0;
        // bf16-P sum is self-consistent with the bf16 PV product below)
        __builtin_amdgcn_s_setprio(1);
        f32x4 lacc = {0.f, 0.f, 0.f, 0.f};
        lacc = MFMA16(ones, pf0, lacc);
        lacc = MFMA16(ones, pf1, lacc);

        // O^T = V^T @ P^T for this qt: lane col = q, regs = 4 consecutive dh
        f32x4 o0 = {0.f, 0.f, 0.f, 0.f}, o1 = {0.f, 0.f, 0.f, 0.f};
        o0 = MFMA16(vf[0][0], pf0, o0);
        o1 = MFMA16(vf[1][0], pf0, o1);
        o0 = MFMA16(vf[0][1], pf1, o0);
        o1 = MFMA16(vf[1][1], pf1, o1);
        __builtin_amdgcn_s_setprio(0);
        float rs = 1.f / lacc[0];   // every reg of lacc holds the same sum

        // O rows -> X region [tok][ch], packed b64, rescaled
        int q = qt * 16 + lr;
        lds_st64(S8 + q * 256 + ((h * 64 + lg * 8) ^ ((q & 7) << 4)),
                 o0[0] * rs, o0[1] * rs, o0[2] * rs, o0[3] * rs);
        lds_st64(S8 + q * 256 + ((h * 64 + 32 + lg * 8) ^ ((q & 7) << 4)),
                 o1[0] * rs, o1[1] * rs, o1[2] * rs, o1[3] * rs);
    }
    __syncthreads();  // B4

    // ---------- proj GEMM + bias -> float4 out ----------
    bf16x8 ofr[4][4];
    #pragma unroll
    for (int tt = 0; tt < 4; ++tt)
        #pragma unroll
        for (int ks = 0; ks < 4; ++ks) {
            int row = tt * 16 + lr;
            ofr[tt][ks] = lds_v8(S8 + row * 256 + ((ks * 64 + lg * 16) ^ ((row & 7) << 4)));
        }
    #pragma unroll
    for (int i = 0; i < 2; ++i) {
        int ct = 2 * h + i;
        bf16x8 wf[4];
        const bf16* wrow = wproj_t + (ct * 16 + lr) * 128 + lg * 8;
        #pragma unroll
        for (int ks = 0; ks < 4; ++ks)
            wf[ks] = *reinterpret_cast<const bf16x8*>(wrow + ks * 32);
        float4 bv = *reinterpret_cast<const float4*>(bias + ct * 16 + lg * 4);
        __builtin_amdgcn_s_setprio(1);
        #pragma unroll
        for (int tt = 0; tt < 4; ++tt) {
            f32x4 a = {0.f, 0.f, 0.f, 0.f};
            #pragma unroll
            for (int ks = 0; ks < 4; ++ks) a = MFMA16(wf[ks], ofr[tt][ks], a);
            int tok = tt * 16 + lr;
            if (tok < NTOK) {
                float4 r = { a[0] + bv.x, a[1] + bv.y, a[2] + bv.z, a[3] + bv.w };
                *reinterpret_cast<float4*>(
                    out + ((size_t)blk * NTOK + tok) * CH + ct * 16 + lg * 4) = r;
            }
        }
        __builtin_amdgcn_s_setprio(0);
    }
}

extern "C" void kernel_launch(void* const* d_in, const int* in_sizes, int n_in,
                              void* d_out, int out_size, void* d_ws, size_t ws_size,
                              hipStream_t stream) {
    const float* x     = (const float*)d_in[0];
    const float* wqkv  = (const float*)d_in[1];
    const float* wproj = (const float*)d_in[2];
    const float* bias  = (const float*)d_in[3];
    float* out = (float*)d_out;
    bf16* ws   = (bf16*)d_ws;

    constexpr size_t WS_NEED = (size_t)(384 * 128 + 128 * 128) * sizeof(u16);
    if (ws_size < WS_NEED) return;

    prep_weights_kernel<<<192, 256, 0, stream>>>(wqkv, wproj, ws);
    fused_window_attn<<<4096, 256, 0, stream>>>(x, ws, ws + 384 * 128, bias, out);
}